// Round 3
// baseline (13231.364 us; speedup 1.0000x reference)
//
#include <hip/hip_runtime.h>
#include <hip/hip_bf16.h>
#include <stdint.h>

typedef unsigned short u16;
typedef float f32x4 __attribute__((ext_vector_type(4)));
typedef short bf16x8 __attribute__((ext_vector_type(8)));

#define NB 32
#define NL 1024
#define ND 512
#define NH 512
#define G4 2048
#define NOUT 100
#define NFF 256

__device__ inline u16 f2b(float f) {
    union { float f; unsigned i; } c; c.f = f;
    unsigned i = c.i;
    return (u16)((i + 0x7FFFu + ((i >> 16) & 1u)) >> 16);
}
// load 8 consecutive fp32, round-to-nearest-even to bf16x8 fragment
__device__ inline bf16x8 cvt8(const float* __restrict__ p) {
    float4 a = *(const float4*)p;
    float4 b = *(const float4*)(p + 4);
    bf16x8 r;
    u16* h = (u16*)&r;
    h[0] = f2b(a.x); h[1] = f2b(a.y); h[2] = f2b(a.z); h[3] = f2b(a.w);
    h[4] = f2b(b.x); h[5] = f2b(b.y); h[6] = f2b(b.z); h[7] = f2b(b.w);
    return r;
}
__device__ inline f32x4 MF(bf16x8 a, bf16x8 b, f32x4 c) {
    return __builtin_amdgcn_mfma_f32_16x16x32_bf16(a, b, c, 0, 0, 0);
}
__device__ inline float tanh_f(float x) {
    float xx = fminf(fmaxf(x, -15.f), 15.f);
    float e = __expf(2.f * xx);
    return (e - 1.f) / (e + 1.f);
}
__device__ inline float sigm_f(float x) { return 1.f / (1.f + __expf(-x)); }

// cbias[b][r] = emb[concepts[b]] . Wih[r, 512:1024] + bih[r] + bhh[r]   (all fp32)
__global__ __launch_bounds__(256) void k_cbias(const float* __restrict__ emb,
                                               const int* __restrict__ concepts,
                                               const float* __restrict__ Wih,
                                               const float* __restrict__ bih,
                                               const float* __restrict__ bhh,
                                               float* __restrict__ cbias) {
    __shared__ float e[ND];
    int b = blockIdx.x;
    int r = blockIdx.y * 256 + threadIdx.x;
    int c = concepts[b];
    for (int i = threadIdx.x; i < ND; i += 256) e[i] = emb[c * ND + i];
    __syncthreads();
    const float* wrow = Wih + (size_t)r * 1024 + 512;
    float acc = 0.f;
#pragma unroll 4
    for (int k4 = 0; k4 < 128; k4++) {
        float4 wv = *(const float4*)&wrow[k4 * 4];
        acc += e[k4 * 4 + 0] * wv.x + e[k4 * 4 + 1] * wv.y +
               e[k4 * 4 + 2] * wv.z + e[k4 * 4 + 3] * wv.w;
    }
    cbias[b * G4 + r] = acc + bih[r] + bhh[r];
}

// Persistent LSTM: 32 blocks, block g owns h lanes [g*16, g*16+16) (64 gate rows).
// fp32 weights converted to bf16 register fragments once; h staged via LDS (bf16).
__global__ __launch_bounds__(512, 1) void k_lstm(const float* __restrict__ x,
                                                 const float* __restrict__ Wih,
                                                 const float* __restrict__ Whh,
                                                 const float* __restrict__ cbias,
                                                 u16* __restrict__ out,
                                                 u16* __restrict__ hbuf,
                                                 int* flags) {
    __shared__ __align__(16) u16 hs[32 * 520];   // 33.3 KB
    __shared__ float gbuf[32 * 72];              // 9.2 KB
    __shared__ float cbuf[512];                  // 2 KB
    int g = blockIdx.x, tid = threadIdx.x;
    int w = tid >> 6, l = tid & 63, quad = l >> 4, lane = l & 15;
    int mt = w & 1, nt = w >> 1;
    int jj = g * 16;
    int rg = nt * NH + jj + lane;    // global gate row for this lane's B fragment
    int bA = mt * 16 + lane;         // batch row for A fragments

    // preload weight fragments (t-invariant), fp32 -> bf16
    bf16x8 wih_f[16], whh_f[16];
#pragma unroll
    for (int kk = 0; kk < 16; kk++) {
        wih_f[kk] = cvt8(&Wih[(size_t)rg * 1024 + kk * 32 + quad * 8]);
        whh_f[kk] = cvt8(&Whh[(size_t)rg * 512 + kk * 32 + quad * 8]);
    }
    f32x4 cbv;
#pragma unroll
    for (int r = 0; r < 4; r++) cbv[r] = cbias[(size_t)(mt * 16 + quad * 4 + r) * G4 + rg];
    cbuf[tid] = 0.f;
    __syncthreads();

    for (int t = 0; t < NL; t++) {
        if (t > 0) {
            if (tid < 32) {
                while (__hip_atomic_load(&flags[tid], __ATOMIC_ACQUIRE,
                                         __HIP_MEMORY_SCOPE_AGENT) < t)
                    __builtin_amdgcn_s_sleep(4);
            }
            __syncthreads();
            const u16* hsrc = hbuf + ((t - 1) & 1) * (NB * NH);
            int row = tid >> 4, seg = tid & 15;
#pragma unroll
            for (int i = 0; i < 8; i++)
                *(uint2*)&hs[row * 520 + seg * 32 + i * 4] =
                    *(const uint2*)&hsrc[row * NH + seg * 32 + i * 4];
            __syncthreads();
        }
        f32x4 acc = cbv;
        const float* xt = x + ((size_t)bA * NL + t) * ND;
#pragma unroll
        for (int kk = 0; kk < 16; kk++)
            acc = MF(cvt8(&xt[kk * 32 + quad * 8]), wih_f[kk], acc);
        if (t > 0) {
#pragma unroll
            for (int kk = 0; kk < 16; kk++)
                acc = MF(*(bf16x8*)&hs[(mt * 16 + lane) * 520 + kk * 32 + quad * 8],
                         whh_f[kk], acc);
        }
#pragma unroll
        for (int r = 0; r < 4; r++)
            gbuf[(mt * 16 + quad * 4 + r) * 72 + nt * 16 + lane] = acc[r];
        __syncthreads();
        {   // cell: one (batch, j) per thread
            int bb = tid >> 4, j = tid & 15;
            float gi = gbuf[bb * 72 + j];
            float gf = gbuf[bb * 72 + 16 + j];
            float gg = gbuf[bb * 72 + 32 + j];
            float go = gbuf[bb * 72 + 48 + j];
            float iv = sigm_f(gi), fv = sigm_f(gf), ov = sigm_f(go);
            float gv = tanh_f(gg);
            float c = fv * cbuf[tid] + iv * gv;
            cbuf[tid] = c;
            u16 hb = f2b(ov * tanh_f(c));
            out[((size_t)bb * NL + t) * NH + jj + j] = hb;
            hbuf[(t & 1) * (NB * NH) + bb * NH + jj + j] = hb;
        }
        __syncthreads();
        if (tid == 0)
            __hip_atomic_store(&flags[g], t + 1, __ATOMIC_RELEASE, __HIP_MEMORY_SCOPE_AGENT);
    }
}

// Fused: Q = x@Wm^T+bm (prologue), flash attention with decayed-causal scores,
// FF head relu(W@W1^T+b1)@W2^T+b2 (epilogue). 16-row q tiles, 512 threads.
// x / Wm / W1 / W2 / biases are fp32 (converted at load); kv is bf16 (internal).
__global__ __launch_bounds__(512) void k_attn(const float* __restrict__ x,
                                              const float* __restrict__ Wm,
                                              const float* __restrict__ bm,
                                              const u16* __restrict__ kv,
                                              const float* __restrict__ W1,
                                              const float* __restrict__ b1,
                                              const float* __restrict__ W2,
                                              const float* __restrict__ b2,
                                              float* __restrict__ outp) {
    __shared__ __align__(16) u16 Qs[16 * 520];   // 16.6 KB (reused as H1)
    __shared__ __align__(16) u16 Vt[512 * 40];   // 40 KB   (reused as Wt)
    __shared__ float Sbuf[16 * 33];              // 2.1 KB
    __shared__ __align__(16) u16 Pbuf[16 * 40];  // 1.3 KB
    __shared__ float alpha_s[16];
    __shared__ float l_s[16];
    int b = blockIdx.x, qt = blockIdx.y;
    int tid = threadIdx.x, w = tid >> 6, l = tid & 63, quad = l >> 4, lane = l & 15;

    // ---- prologue: Qs[16][512] = x_tile @ Wm^T + bm
    {
        const float* xq = x + ((size_t)b * NL + qt * 16 + lane) * ND;
#pragma unroll
        for (int nt2 = 0; nt2 < 4; nt2++) {
            int n = (w * 4 + nt2) * 16 + lane;
            const float* wmp = Wm + (size_t)n * ND;
            f32x4 aq = {};
#pragma unroll 4
            for (int kk = 0; kk < 16; kk++)
                aq = MF(cvt8(&xq[kk * 32 + quad * 8]), cvt8(&wmp[kk * 32 + quad * 8]), aq);
            float bmv = bm[n];
#pragma unroll
            for (int r = 0; r < 4; r++)
                Qs[(quad * 4 + r) * 520 + n] = f2b(aq[r] + bmv);
        }
    }
    float m_run = -30000.f, l_run = 0.f;
    f32x4 acc[4] = {};
    __syncthreads();

    int st_max = ((qt << 4) + 15) >> 5;
    for (int st = 0; st <= st_max; st++) {
        if (w < 2) {  // QK^T: S[16][32], waves 0..1
            int ni = w;
            f32x4 s = {};
            const u16* krow = kv + ((size_t)b * NL + st * 32 + ni * 16 + lane) * NH;
#pragma unroll 4
            for (int kk = 0; kk < 16; kk++)
                s = MF(*(bf16x8*)&Qs[lane * 520 + kk * 32 + quad * 8],
                       *(const bf16x8*)&krow[kk * 32 + quad * 8], s);
            int scol = st * 32 + ni * 16 + lane;
#pragma unroll
            for (int r = 0; r < 4; r++) {
                int trow = (qt << 4) + quad * 4 + r;
                int dt = trow - scol;
                float v = (dt < 0) ? -30000.f : s[r] * __expf(-0.6f * (float)dt);
                Sbuf[(quad * 4 + r) * 33 + ni * 16 + lane] = v;
            }
        } else if (w >= 4) {  // stage V^T[512][32]
            int t2 = tid & 255;
            int srow = t2 >> 3, dseg = t2 & 7;
            const u16* vsrc = kv + ((size_t)b * NL + st * 32 + srow) * NH + dseg * 64;
#pragma unroll
            for (int i = 0; i < 8; i++) {
                union { uint4 v; u16 h[8]; } u;
                u.v = *(const uint4*)&vsrc[i * 8];
                int d0 = dseg * 64 + i * 8;
#pragma unroll
                for (int j2 = 0; j2 < 8; j2++) Vt[(d0 + j2) * 40 + srow] = u.h[j2];
            }
        }
        __syncthreads();
        if (tid < 16) {  // online softmax, one row per thread
            int m = tid;
            float vmax = -30000.f;
#pragma unroll 8
            for (int n = 0; n < 32; n++) vmax = fmaxf(vmax, Sbuf[m * 33 + n]);
            float mnew = fmaxf(m_run, vmax);
            float al = __expf(m_run - mnew);
            float lsum = 0.f;
#pragma unroll 8
            for (int n = 0; n < 32; n++) {
                float p = __expf(Sbuf[m * 33 + n] - mnew);
                lsum += p;
                Pbuf[m * 40 + n] = f2b(p);
            }
            l_run = l_run * al + lsum;
            m_run = mnew;
            alpha_s[m] = al;
            l_s[m] = l_run;
        }
        __syncthreads();
        {   // PV: each wave 4 dtiles (64 d-cols)
            float a0 = alpha_s[quad * 4 + 0];
            float a1 = alpha_s[quad * 4 + 1];
            float a2 = alpha_s[quad * 4 + 2];
            float a3 = alpha_s[quad * 4 + 3];
            bf16x8 afrag = *(bf16x8*)&Pbuf[lane * 40 + quad * 8];
#pragma unroll
            for (int di = 0; di < 4; di++) {
                int dtile = w * 4 + di;
                f32x4 c = acc[di];
                c[0] *= a0; c[1] *= a1; c[2] *= a2; c[3] *= a3;
                acc[di] = MF(afrag, *(bf16x8*)&Vt[(dtile * 16 + lane) * 40 + quad * 8], c);
            }
        }
        __syncthreads();
    }

    // ---- epilogue: weighted -> LDS (reuse Vt as bf16 [16][520]), then FF head
    u16* Wt = Vt;
    {
        float li0 = 1.f / l_s[quad * 4 + 0];
        float li1 = 1.f / l_s[quad * 4 + 1];
        float li2 = 1.f / l_s[quad * 4 + 2];
        float li3 = 1.f / l_s[quad * 4 + 3];
#pragma unroll
        for (int di = 0; di < 4; di++) {
            int col = (w * 4 + di) * 16 + lane;
            Wt[(quad * 4 + 0) * 520 + col] = f2b(acc[di][0] * li0);
            Wt[(quad * 4 + 1) * 520 + col] = f2b(acc[di][1] * li1);
            Wt[(quad * 4 + 2) * 520 + col] = f2b(acc[di][2] * li2);
            Wt[(quad * 4 + 3) * 520 + col] = f2b(acc[di][3] * li3);
        }
    }
    __syncthreads();
    u16* H1 = Qs;  // reuse
    {   // H1[16][256] = relu(Wt @ W1^T + b1)
#pragma unroll
        for (int nt2 = 0; nt2 < 2; nt2++) {
            int n = (w * 2 + nt2) * 16 + lane;
            const float* w1p = W1 + (size_t)n * ND;
            f32x4 a1 = {};
#pragma unroll 4
            for (int kk = 0; kk < 16; kk++)
                a1 = MF(*(bf16x8*)&Wt[lane * 520 + kk * 32 + quad * 8],
                        cvt8(&w1p[kk * 32 + quad * 8]), a1);
            float b1v = b1[n];
#pragma unroll
            for (int r = 0; r < 4; r++)
                H1[(quad * 4 + r) * 264 + n] = f2b(fmaxf(a1[r] + b1v, 0.f));
        }
    }
    __syncthreads();
    if (w < 7) {  // out[16][100] = H1 @ W2^T + b2   (fp32 store)
        int n = w * 16 + lane;
        int nc = n < NOUT ? n : NOUT - 1;
        const float* w2p = W2 + (size_t)nc * NFF;
        f32x4 a2 = {};
#pragma unroll
        for (int kk = 0; kk < 8; kk++)
            a2 = MF(*(bf16x8*)&H1[lane * 264 + kk * 32 + quad * 8],
                    cvt8(&w2p[kk * 32 + quad * 8]), a2);
        if (n < NOUT) {
            float b2v = b2[n];
#pragma unroll
            for (int r = 0; r < 4; r++)
                outp[((size_t)b * NL + (qt << 4) + quad * 4 + r) * NOUT + n] = a2[r] + b2v;
        }
    }
}

extern "C" void kernel_launch(void* const* d_in, const int* in_sizes, int n_in,
                              void* d_out, int out_size, void* d_ws, size_t ws_size,
                              hipStream_t stream) {
    const float* x        = (const float*)d_in[0];
    const int*   concepts = (const int*)d_in[1];
    const float* emb      = (const float*)d_in[2];
    const float* Wih      = (const float*)d_in[3];
    const float* Whh      = (const float*)d_in[4];
    const float* bih      = (const float*)d_in[5];
    const float* bhh      = (const float*)d_in[6];
    const float* Wm       = (const float*)d_in[7];
    const float* bm       = (const float*)d_in[8];
    const float* W1       = (const float*)d_in[9];
    const float* b1       = (const float*)d_in[10];
    const float* W2       = (const float*)d_in[11];
    const float* b2       = (const float*)d_in[12];
    float* outp = (float*)d_out;

    char* ws = (char*)d_ws;
    size_t off = 0;
    u16* lstm_out = (u16*)(ws + off); off += (size_t)NB * NL * NH * 2;  // 32 MB
    float* cbias  = (float*)(ws + off); off += (size_t)NB * G4 * 4;     // 256 KB
    u16* hbuf     = (u16*)(ws + off); off += (size_t)2 * NB * NH * 2;   // 64 KB
    int* flags    = (int*)(ws + off); off += 256;                        // ~32.4 MB total

    hipMemsetAsync(flags, 0, 256, stream);
    k_cbias<<<dim3(NB, G4 / 256), 256, 0, stream>>>(emb, concepts, Wih, bih, bhh, cbias);
    k_lstm<<<32, 512, 0, stream>>>(x, Wih, Whh, cbias, lstm_out, hbuf, flags);
    k_attn<<<dim3(NB, NL / 16), 512, 0, stream>>>(x, Wm, bm, lstm_out, W1, b1, W2, b2, outp);
}

// Round 4
// 11184.736 us; speedup vs baseline: 1.1830x; 1.1830x over previous
//
#include <hip/hip_runtime.h>
#include <hip/hip_bf16.h>
#include <stdint.h>

typedef unsigned short u16;
typedef unsigned long long u64;
typedef float f32x4 __attribute__((ext_vector_type(4)));
typedef short bf16x8 __attribute__((ext_vector_type(8)));

#define NB 32
#define NL 1024
#define ND 512
#define NH 512
#define G4 2048
#define NOUT 100
#define NFF 256

__device__ inline u16 f2b(float f) {
    union { float f; unsigned i; } c; c.f = f;
    unsigned i = c.i;
    return (u16)((i + 0x7FFFu + ((i >> 16) & 1u)) >> 16);
}
__device__ inline bf16x8 cvt8(const float* __restrict__ p) {
    float4 a = *(const float4*)p;
    float4 b = *(const float4*)(p + 4);
    bf16x8 r;
    u16* h = (u16*)&r;
    h[0] = f2b(a.x); h[1] = f2b(a.y); h[2] = f2b(a.z); h[3] = f2b(a.w);
    h[4] = f2b(b.x); h[5] = f2b(b.y); h[6] = f2b(b.z); h[7] = f2b(b.w);
    return r;
}
__device__ inline f32x4 MF(bf16x8 a, bf16x8 b, f32x4 c) {
    return __builtin_amdgcn_mfma_f32_16x16x32_bf16(a, b, c, 0, 0, 0);
}
__device__ inline float tanh_f(float x) {
    float xx = fminf(fmaxf(x, -15.f), 15.f);
    float e = __expf(2.f * xx);
    return (e - 1.f) / (e + 1.f);
}
__device__ inline float sigm_f(float x) { return 1.f / (1.f + __expf(-x)); }

// cbias[b][r] = emb[concepts[b]] . Wih[r, 512:1024] + bih[r] + bhh[r]   (all fp32)
__global__ __launch_bounds__(256) void k_cbias(const float* __restrict__ emb,
                                               const int* __restrict__ concepts,
                                               const float* __restrict__ Wih,
                                               const float* __restrict__ bih,
                                               const float* __restrict__ bhh,
                                               float* __restrict__ cbias) {
    __shared__ float e[ND];
    int b = blockIdx.x;
    int r = blockIdx.y * 256 + threadIdx.x;
    int c = concepts[b];
    for (int i = threadIdx.x; i < ND; i += 256) e[i] = emb[c * ND + i];
    __syncthreads();
    const float* wrow = Wih + (size_t)r * 1024 + 512;
    float acc = 0.f;
#pragma unroll 4
    for (int k4 = 0; k4 < 128; k4++) {
        float4 wv = *(const float4*)&wrow[k4 * 4];
        acc += e[k4 * 4 + 0] * wv.x + e[k4 * 4 + 1] * wv.y +
               e[k4 * 4 + 2] * wv.z + e[k4 * 4 + 3] * wv.w;
    }
    cbias[b * G4 + r] = acc + bih[r] + bhh[r];
}

// Persistent LSTM: 32 blocks, block g owns h lanes [g*16, g*16+16) (64 gate rows).
// Weights live in VGPRs. Cross-block h exchange via RELAXED agent-scope atomics
// (point-coherent at IF — no buffer_inv/wbl2 cache maintenance in the loop).
// Arrival counter cnt[t]; readers poll cnt[t-1]==32 with relaxed loads.
__global__ __launch_bounds__(512, 1) void k_lstm(const float* __restrict__ x,
                                                 const float* __restrict__ Wih,
                                                 const float* __restrict__ Whh,
                                                 const float* __restrict__ cbias,
                                                 u16* __restrict__ out,
                                                 u64* __restrict__ h64,
                                                 int* __restrict__ cnt) {
    __shared__ __align__(16) u16 hs[32 * 520];   // 33.3 KB
    __shared__ float gbuf[32 * 72];              // 9.2 KB
    __shared__ float cbuf[512];                  // 2 KB
    int g = blockIdx.x, tid = threadIdx.x;
    int w = tid >> 6, l = tid & 63, quad = l >> 4, lane = l & 15;
    int mt = w & 1, nt = w >> 1;
    int jj = g * 16;
    int rg = nt * NH + jj + lane;    // global gate row for this lane's B fragment
    int bA = mt * 16 + lane;         // batch row for A fragments

    // preload weight fragments (t-invariant), fp32 -> bf16
    bf16x8 wih_f[16], whh_f[16];
#pragma unroll
    for (int kk = 0; kk < 16; kk++) {
        wih_f[kk] = cvt8(&Wih[(size_t)rg * 1024 + kk * 32 + quad * 8]);
        whh_f[kk] = cvt8(&Whh[(size_t)rg * 512 + kk * 32 + quad * 8]);
    }
    f32x4 cbv;
#pragma unroll
    for (int r = 0; r < 4; r++) cbv[r] = cbias[(size_t)(mt * 16 + quad * 4 + r) * G4 + rg];
    cbuf[tid] = 0.f;
    __syncthreads();

    for (int t = 0; t < NL; t++) {
        // ---- x-part first (independent of h exchange)
        f32x4 acc = cbv;
        const float* xt = x + ((size_t)bA * NL + t) * ND;
#pragma unroll
        for (int kk = 0; kk < 16; kk++)
            acc = MF(cvt8(&xt[kk * 32 + quad * 8]), wih_f[kk], acc);

        if (t > 0) {
            if (tid == 0) {
                while (__hip_atomic_load(&cnt[t - 1], __ATOMIC_RELAXED,
                                         __HIP_MEMORY_SCOPE_AGENT) < NB)
                    __builtin_amdgcn_s_sleep(1);
            }
            __syncthreads();   // (A) release pollers; hs safe to overwrite
            {   // stage h[t-1] (relaxed atomic u64 loads -> LDS)
                int row = tid >> 4, seg = tid & 15;
                const u64* src = h64 + (size_t)((t - 1) & 1) * 4096 + row * 128 + seg * 8;
#pragma unroll
                for (int i = 0; i < 8; i++) {
                    u64 v = __hip_atomic_load(&src[i], __ATOMIC_RELAXED,
                                              __HIP_MEMORY_SCOPE_AGENT);
                    *(u64*)((char*)hs + row * 1040 + seg * 64 + i * 8) = v;
                }
            }
            __syncthreads();   // (C)
#pragma unroll
            for (int kk = 0; kk < 16; kk++)
                acc = MF(*(bf16x8*)&hs[(mt * 16 + lane) * 520 + kk * 32 + quad * 8],
                         whh_f[kk], acc);
        }
#pragma unroll
        for (int r = 0; r < 4; r++)
            gbuf[(mt * 16 + quad * 4 + r) * 72 + nt * 16 + lane] = acc[r];
        __syncthreads();       // (B)
        {   // cell: one (batch, j) per thread; pack 4 bf16 -> one relaxed atomic u64
            int bb = tid >> 4, j = tid & 15;
            float gi = gbuf[bb * 72 + j];
            float gf = gbuf[bb * 72 + 16 + j];
            float gg = gbuf[bb * 72 + 32 + j];
            float go = gbuf[bb * 72 + 48 + j];
            float iv = sigm_f(gi), fv = sigm_f(gf), ov = sigm_f(go);
            float gv = tanh_f(gg);
            float c = fv * cbuf[tid] + iv * gv;
            cbuf[tid] = c;
            u16 hb = f2b(ov * tanh_f(c));
            out[((size_t)bb * NL + t) * NH + jj + j] = hb;
            unsigned hb32 = (unsigned)hb;
            unsigned v1 = __shfl_down(hb32, 1);
            unsigned v2 = __shfl_down(hb32, 2);
            unsigned v3 = __shfl_down(hb32, 3);
            if ((j & 3) == 0) {
                u64 pk = (u64)hb32 | ((u64)v1 << 16) | ((u64)v2 << 32) | ((u64)v3 << 48);
                __hip_atomic_store(&h64[(size_t)(t & 1) * 4096 + bb * 128 + ((jj + j) >> 2)],
                                   pk, __ATOMIC_RELAXED, __HIP_MEMORY_SCOPE_AGENT);
            }
        }
        __syncthreads();       // (D) drains each wave's vmcnt before announce
        if (tid == 0)
            __hip_atomic_fetch_add(&cnt[t], 1, __ATOMIC_RELAXED, __HIP_MEMORY_SCOPE_AGENT);
    }
}

// Fused: Q = x@Wm^T+bm (prologue), flash attention with decayed-causal scores,
// FF head relu(W@W1^T+b1)@W2^T+b2 (epilogue). 16-row q tiles, 512 threads.
__global__ __launch_bounds__(512) void k_attn(const float* __restrict__ x,
                                              const float* __restrict__ Wm,
                                              const float* __restrict__ bm,
                                              const u16* __restrict__ kv,
                                              const float* __restrict__ W1,
                                              const float* __restrict__ b1,
                                              const float* __restrict__ W2,
                                              const float* __restrict__ b2,
                                              float* __restrict__ outp) {
    __shared__ __align__(16) u16 Qs[16 * 520];   // 16.6 KB (reused as H1)
    __shared__ __align__(16) u16 Vt[512 * 40];   // 40 KB   (reused as Wt)
    __shared__ float Sbuf[16 * 33];              // 2.1 KB
    __shared__ __align__(16) u16 Pbuf[16 * 40];  // 1.3 KB
    __shared__ float alpha_s[16];
    __shared__ float l_s[16];
    int b = blockIdx.x, qt = blockIdx.y;
    int tid = threadIdx.x, w = tid >> 6, l = tid & 63, quad = l >> 4, lane = l & 15;

    {   // prologue: Qs[16][512] = x_tile @ Wm^T + bm
        const float* xq = x + ((size_t)b * NL + qt * 16 + lane) * ND;
#pragma unroll
        for (int nt2 = 0; nt2 < 4; nt2++) {
            int n = (w * 4 + nt2) * 16 + lane;
            const float* wmp = Wm + (size_t)n * ND;
            f32x4 aq = {};
#pragma unroll 4
            for (int kk = 0; kk < 16; kk++)
                aq = MF(cvt8(&xq[kk * 32 + quad * 8]), cvt8(&wmp[kk * 32 + quad * 8]), aq);
            float bmv = bm[n];
#pragma unroll
            for (int r = 0; r < 4; r++)
                Qs[(quad * 4 + r) * 520 + n] = f2b(aq[r] + bmv);
        }
    }
    float m_run = -30000.f, l_run = 0.f;
    f32x4 acc[4] = {};
    __syncthreads();

    int st_max = ((qt << 4) + 15) >> 5;
    for (int st = 0; st <= st_max; st++) {
        if (w < 2) {  // QK^T: S[16][32], waves 0..1
            int ni = w;
            f32x4 s = {};
            const u16* krow = kv + ((size_t)b * NL + st * 32 + ni * 16 + lane) * NH;
#pragma unroll 4
            for (int kk = 0; kk < 16; kk++)
                s = MF(*(bf16x8*)&Qs[lane * 520 + kk * 32 + quad * 8],
                       *(const bf16x8*)&krow[kk * 32 + quad * 8], s);
            int scol = st * 32 + ni * 16 + lane;
#pragma unroll
            for (int r = 0; r < 4; r++) {
                int trow = (qt << 4) + quad * 4 + r;
                int dt = trow - scol;
                float v = (dt < 0) ? -30000.f : s[r] * __expf(-0.6f * (float)dt);
                Sbuf[(quad * 4 + r) * 33 + ni * 16 + lane] = v;
            }
        } else if (w >= 4) {  // stage V^T[512][32]
            int t2 = tid & 255;
            int srow = t2 >> 3, dseg = t2 & 7;
            const u16* vsrc = kv + ((size_t)b * NL + st * 32 + srow) * NH + dseg * 64;
#pragma unroll
            for (int i = 0; i < 8; i++) {
                union { uint4 v; u16 h[8]; } u;
                u.v = *(const uint4*)&vsrc[i * 8];
                int d0 = dseg * 64 + i * 8;
#pragma unroll
                for (int j2 = 0; j2 < 8; j2++) Vt[(d0 + j2) * 40 + srow] = u.h[j2];
            }
        }
        __syncthreads();
        if (tid < 16) {  // online softmax, one row per thread
            int m = tid;
            float vmax = -30000.f;
#pragma unroll 8
            for (int n = 0; n < 32; n++) vmax = fmaxf(vmax, Sbuf[m * 33 + n]);
            float mnew = fmaxf(m_run, vmax);
            float al = __expf(m_run - mnew);
            float lsum = 0.f;
#pragma unroll 8
            for (int n = 0; n < 32; n++) {
                float p = __expf(Sbuf[m * 33 + n] - mnew);
                lsum += p;
                Pbuf[m * 40 + n] = f2b(p);
            }
            l_run = l_run * al + lsum;
            m_run = mnew;
            alpha_s[m] = al;
            l_s[m] = l_run;
        }
        __syncthreads();
        {   // PV: each wave 4 dtiles (64 d-cols)
            float a0 = alpha_s[quad * 4 + 0];
            float a1 = alpha_s[quad * 4 + 1];
            float a2 = alpha_s[quad * 4 + 2];
            float a3 = alpha_s[quad * 4 + 3];
            bf16x8 afrag = *(bf16x8*)&Pbuf[lane * 40 + quad * 8];
#pragma unroll
            for (int di = 0; di < 4; di++) {
                int dtile = w * 4 + di;
                f32x4 c = acc[di];
                c[0] *= a0; c[1] *= a1; c[2] *= a2; c[3] *= a3;
                acc[di] = MF(afrag, *(bf16x8*)&Vt[(dtile * 16 + lane) * 40 + quad * 8], c);
            }
        }
        __syncthreads();
    }

    // ---- epilogue: weighted -> LDS (reuse Vt as bf16 [16][520]), then FF head
    u16* Wt = Vt;
    {
        float li0 = 1.f / l_s[quad * 4 + 0];
        float li1 = 1.f / l_s[quad * 4 + 1];
        float li2 = 1.f / l_s[quad * 4 + 2];
        float li3 = 1.f / l_s[quad * 4 + 3];
#pragma unroll
        for (int di = 0; di < 4; di++) {
            int col = (w * 4 + di) * 16 + lane;
            Wt[(quad * 4 + 0) * 520 + col] = f2b(acc[di][0] * li0);
            Wt[(quad * 4 + 1) * 520 + col] = f2b(acc[di][1] * li1);
            Wt[(quad * 4 + 2) * 520 + col] = f2b(acc[di][2] * li2);
            Wt[(quad * 4 + 3) * 520 + col] = f2b(acc[di][3] * li3);
        }
    }
    __syncthreads();
    u16* H1 = Qs;  // reuse
    {   // H1[16][256] = relu(Wt @ W1^T + b1)
#pragma unroll
        for (int nt2 = 0; nt2 < 2; nt2++) {
            int n = (w * 2 + nt2) * 16 + lane;
            const float* w1p = W1 + (size_t)n * ND;
            f32x4 a1 = {};
#pragma unroll 4
            for (int kk = 0; kk < 16; kk++)
                a1 = MF(*(bf16x8*)&Wt[lane * 520 + kk * 32 + quad * 8],
                        cvt8(&w1p[kk * 32 + quad * 8]), a1);
            float b1v = b1[n];
#pragma unroll
            for (int r = 0; r < 4; r++)
                H1[(quad * 4 + r) * 264 + n] = f2b(fmaxf(a1[r] + b1v, 0.f));
        }
    }
    __syncthreads();
    if (w < 7) {  // out[16][100] = H1 @ W2^T + b2   (fp32 store)
        int n = w * 16 + lane;
        int nc = n < NOUT ? n : NOUT - 1;
        const float* w2p = W2 + (size_t)nc * NFF;
        f32x4 a2 = {};
#pragma unroll
        for (int kk = 0; kk < 8; kk++)
            a2 = MF(*(bf16x8*)&H1[lane * 264 + kk * 32 + quad * 8],
                    cvt8(&w2p[kk * 32 + quad * 8]), a2);
        if (n < NOUT) {
            float b2v = b2[n];
#pragma unroll
            for (int r = 0; r < 4; r++)
                outp[((size_t)b * NL + (qt << 4) + quad * 4 + r) * NOUT + n] = a2[r] + b2v;
        }
    }
}

extern "C" void kernel_launch(void* const* d_in, const int* in_sizes, int n_in,
                              void* d_out, int out_size, void* d_ws, size_t ws_size,
                              hipStream_t stream) {
    const float* x        = (const float*)d_in[0];
    const int*   concepts = (const int*)d_in[1];
    const float* emb      = (const float*)d_in[2];
    const float* Wih      = (const float*)d_in[3];
    const float* Whh      = (const float*)d_in[4];
    const float* bih      = (const float*)d_in[5];
    const float* bhh      = (const float*)d_in[6];
    const float* Wm       = (const float*)d_in[7];
    const float* bm       = (const float*)d_in[8];
    const float* W1       = (const float*)d_in[9];
    const float* b1       = (const float*)d_in[10];
    const float* W2       = (const float*)d_in[11];
    const float* b2       = (const float*)d_in[12];
    float* outp = (float*)d_out;

    char* ws = (char*)d_ws;
    size_t off = 0;
    u16* lstm_out = (u16*)(ws + off); off += (size_t)NB * NL * NH * 2;  // 32 MB
    float* cbias  = (float*)(ws + off); off += (size_t)NB * G4 * 4;     // 256 KB
    u64* h64      = (u64*)(ws + off); off += (size_t)2 * 4096 * 8;      // 64 KB
    int* cnt      = (int*)(ws + off); off += NL * 4;                     // 4 KB

    hipMemsetAsync(cnt, 0, NL * 4, stream);
    k_cbias<<<dim3(NB, G4 / 256), 256, 0, stream>>>(emb, concepts, Wih, bih, bhh, cbias);
    k_lstm<<<32, 512, 0, stream>>>(x, Wih, Whh, cbias, lstm_out, h64, cnt);
    k_attn<<<dim3(NB, NL / 16), 512, 0, stream>>>(x, Wm, bm, lstm_out, W1, b1, W2, b2, outp);
}